// Round 1
// baseline (907.818 us; speedup 1.0000x reference)
//
#include <hip/hip_runtime.h>
#include <hip/hip_bf16.h>

#define SEQ   110
#define HALFS 55
#define EMB   102
#define HEAD  192

typedef short bf16x8 __attribute__((ext_vector_type(8)));
typedef short bf16x4 __attribute__((ext_vector_type(4)));
typedef float f32x4  __attribute__((ext_vector_type(4)));

#define XS   104              // x_lds row stride (bf16), 13 16B-granules (odd -> conflict-free)
#define QS   200              // q/k row stride, 25 granules (odd)
#define VS   72               // vT row stride, 9 granules (odd)
#define PS   72               // P row stride
#define WES  128              // Wt e-stride (padded 102->128)
#define WMAT (HEAD * WES)     // 24576 elements per weight matrix

__device__ __forceinline__ short f2bf(float f) {
    unsigned u = __float_as_uint(f);
    unsigned r = u + 0x7fffu + ((u >> 16) & 1u);   // round-to-nearest-even
    return (short)(r >> 16);
}

// Transpose + pad + convert weights: Wt[m][h][e] = W_m[e][h], bf16, zeros for e>=102.
__global__ void wt_prep(const float* __restrict__ Wq, const float* __restrict__ Wk,
                        const float* __restrict__ Wv, short* __restrict__ wt) {
    int flat = blockIdx.x * 256 + threadIdx.x;     // < 3*24576
    int m   = flat / WMAT;
    int rem = flat - m * WMAT;
    int h = rem >> 7;
    int e = rem & 127;
    const float* W = (m == 0) ? Wq : (m == 1) ? Wk : Wv;
    float v = (e < EMB) ? W[e * HEAD + h] : 0.0f;
    wt[flat] = f2bf(v);
}

// One block per (batch, half): queries = own half (55 rows), keys/values = other half.
__global__ __launch_bounds__(256, 2)
void attn_head(const float* __restrict__ x, const short* __restrict__ wt,
               float* __restrict__ out) {
    const int bid   = blockIdx.x;
    const int batch = bid >> 1;
    const int half  = bid & 1;
    const int tid   = threadIdx.x;
    const int w     = tid >> 6;       // wave 0..3
    const int lane  = tid & 63;
    const int g     = lane >> 4;      // 0..3
    const int r     = lane & 15;

    __shared__ __attribute__((aligned(16))) short q_lds[64 * QS];     // 25600 B
    __shared__ __attribute__((aligned(16))) short k_lds[64 * QS];     // 25600 B
    __shared__ __attribute__((aligned(16))) short xv_lds[HEAD * VS];  // 27648 B; x uses first 26624 B

    // ---- zero x staging region (covers row/col zero-padding) ----
    {
        unsigned long long* z = (unsigned long long*)xv_lds;
        #pragma unroll
        for (int i = 0; i < 13; ++i) z[tid + 256 * i] = 0ull;   // 13*256 u64 = 26624 B
    }
    __syncthreads();

    // ---- stage x[batch] -> bf16, two zero-padded [64][XS] tiles (half0 rows, half1 rows) ----
    {
        const float4* xb4 = (const float4*)(x + (size_t)batch * (SEQ * EMB));
        for (int it = 0; it < 11; ++it) {
            int i4 = tid + it * 256;
            if (i4 < (SEQ * EMB) / 4) {          // 2805 float4
                float4 v4 = xb4[i4];
                float vals[4] = {v4.x, v4.y, v4.z, v4.w};
                #pragma unroll
                for (int c = 0; c < 4; ++c) {
                    int fc   = i4 * 4 + c;
                    int row  = (int)(((unsigned long long)fc * 41121ull) >> 22);  // /102
                    int e    = fc - row * EMB;
                    int tile = (row >= HALFS);
                    int lr   = row - tile * HALFS;
                    xv_lds[tile * (64 * XS) + lr * XS + e] = f2bf(vals[c]);
                }
            }
        }
    }
    __syncthreads();

    const short* x_own = &xv_lds[half * (64 * XS)];
    const short* x_oth = &xv_lds[(half ^ 1) * (64 * XS)];
    const short* wtq = wt;
    const short* wtk = wt + WMAT;
    const short* wtv = wt + 2 * WMAT;

    // ---- x B-frags for q/k GEMMs (wave's 16 s-columns: rows 16w+r) ----
    bf16x8 bxq[4], bxk[4];
    {
        const short* bo = x_own + (16 * w + r) * XS;
        const short* bt = x_oth + (16 * w + r) * XS;
        #pragma unroll
        for (int kk = 0; kk < 3; ++kk) {
            bxq[kk] = *(const bf16x8*)(bo + 32 * kk + 8 * g);
            bxk[kk] = *(const bf16x8*)(bt + 32 * kk + 8 * g);
        }
        bf16x8 zz = {};
        bxq[3] = zz; bxk[3] = zz;
        if (g == 0) {                 // tail K-step: only e=96..103 exists (102,103 are zeros)
            bxq[3] = *(const bf16x8*)(bo + 96);
            bxk[3] = *(const bf16x8*)(bt + 96);
        }
    }

    const float qscale = 0.07216878364870322f;   // 1/sqrt(192), folded into q

    // ---- q-GEMM: qT = WtQ @ x_ownT ; C col = s (=16w+r), rows = h -> contiguous b64 writes ----
    #pragma unroll
    for (int mt = 0; mt < 12; ++mt) {
        const short* wb = wtq + (16 * mt + r) * WES + 8 * g;
        f32x4 acc = {0.f, 0.f, 0.f, 0.f};
        #pragma unroll
        for (int kk = 0; kk < 4; ++kk)
            acc = __builtin_amdgcn_mfma_f32_16x16x32_bf16(
                *(const bf16x8*)(wb + 32 * kk), bxq[kk], acc, 0, 0, 0);
        bf16x4 pk;
        #pragma unroll
        for (int j = 0; j < 4; ++j) pk[j] = f2bf(acc[j] * qscale);
        *(bf16x4*)(&q_lds[(16 * w + r) * QS + 16 * mt + 4 * g]) = pk;
    }

    // ---- k-GEMM (same, other half, no scale) ----
    #pragma unroll
    for (int mt = 0; mt < 12; ++mt) {
        const short* wb = wtk + (16 * mt + r) * WES + 8 * g;
        f32x4 acc = {0.f, 0.f, 0.f, 0.f};
        #pragma unroll
        for (int kk = 0; kk < 4; ++kk)
            acc = __builtin_amdgcn_mfma_f32_16x16x32_bf16(
                *(const bf16x8*)(wb + 32 * kk), bxk[kk], acc, 0, 0, 0);
        bf16x4 pk;
        #pragma unroll
        for (int j = 0; j < 4; ++j) pk[j] = f2bf(acc[j]);
        *(bf16x4*)(&k_lds[(16 * w + r) * QS + 16 * mt + 4 * g]) = pk;
    }

    // ---- v-GEMM: v = x_oth @ Wv ; wave owns h-tiles {w, w+4, w+8}; acc held in regs ----
    bf16x8 bv[3][4];
    #pragma unroll
    for (int i = 0; i < 3; ++i) {
        const short* wb = wtv + (16 * (w + 4 * i) + r) * WES + 8 * g;
        #pragma unroll
        for (int kk = 0; kk < 4; ++kk) bv[i][kk] = *(const bf16x8*)(wb + 32 * kk);
    }
    f32x4 vacc[4][3];
    #pragma unroll
    for (int mt = 0; mt < 4; ++mt) {
        #pragma unroll
        for (int i = 0; i < 3; ++i) { f32x4 zz = {0.f,0.f,0.f,0.f}; vacc[mt][i] = zz; }
    }
    #pragma unroll
    for (int mt = 0; mt < 4; ++mt) {
        const short* ab = x_oth + (16 * mt + r) * XS;
        bf16x8 a[4];
        #pragma unroll
        for (int kk = 0; kk < 3; ++kk) a[kk] = *(const bf16x8*)(ab + 32 * kk + 8 * g);
        bf16x8 zz = {};
        a[3] = zz;
        if (g == 0) a[3] = *(const bf16x8*)(ab + 96);
        #pragma unroll
        for (int i = 0; i < 3; ++i) {
            #pragma unroll
            for (int kk = 0; kk < 4; ++kk)
                vacc[mt][i] = __builtin_amdgcn_mfma_f32_16x16x32_bf16(
                    a[kk], bv[i][kk], vacc[mt][i], 0, 0, 0);
        }
    }

    __syncthreads();   // all x reads and q/k LDS writes complete

    // ---- write vT (overlays the x region); C col = h, rows = s -> contiguous b64 ----
    #pragma unroll
    for (int mt = 0; mt < 4; ++mt) {
        #pragma unroll
        for (int i = 0; i < 3; ++i) {
            int h = 16 * (w + 4 * i) + r;
            bf16x4 pk;
            #pragma unroll
            for (int j = 0; j < 4; ++j) pk[j] = f2bf(vacc[mt][i][j]);
            *(bf16x4*)(&xv_lds[h * VS + 16 * mt + 4 * g]) = pk;
        }
    }

    __syncthreads();   // vT visible to all waves

    // ---- scoresT = k @ qT for this wave's 16 query columns (s = 16w+r) ----
    bf16x8 bq[6];
    {
        const short* qb = &q_lds[(16 * w + r) * QS + 8 * g];
        #pragma unroll
        for (int kk = 0; kk < 6; ++kk) bq[kk] = *(const bf16x8*)(qb + 32 * kk);
    }
    float sc[4][4];    // [mt_t][j] : t = 16*mt + 4*g + j, one query s = 16w+r per lane
    #pragma unroll
    for (int mt = 0; mt < 4; ++mt) {
        const short* kb = &k_lds[(16 * mt + r) * QS + 8 * g];
        f32x4 acc = {0.f, 0.f, 0.f, 0.f};
        #pragma unroll
        for (int kk = 0; kk < 6; ++kk)
            acc = __builtin_amdgcn_mfma_f32_16x16x32_bf16(
                *(const bf16x8*)(kb + 32 * kk), bq[kk], acc, 0, 0, 0);
        #pragma unroll
        for (int j = 0; j < 4; ++j) sc[mt][j] = acc[j];
    }
    // mask key padding: t = 48 + 4g + j >= 55 (only mt=3 affected)
    #pragma unroll
    for (int j = 0; j < 4; ++j)
        if (48 + 4 * g + j >= HALFS) sc[3][j] = -1e30f;

    // softmax over t: 16 in-lane values + reduce across the 4 g-groups
    float mx = -1e30f;
    #pragma unroll
    for (int mt = 0; mt < 4; ++mt) {
        #pragma unroll
        for (int j = 0; j < 4; ++j) mx = fmaxf(mx, sc[mt][j]);
    }
    mx = fmaxf(mx, __shfl_xor(mx, 16));
    mx = fmaxf(mx, __shfl_xor(mx, 32));

    float p[4][4];
    float sum = 0.f;
    #pragma unroll
    for (int mt = 0; mt < 4; ++mt) {
        #pragma unroll
        for (int j = 0; j < 4; ++j) { p[mt][j] = __expf(sc[mt][j] - mx); sum += p[mt][j]; }
    }
    sum += __shfl_xor(sum, 16);
    sum += __shfl_xor(sum, 32);
    float rs = 1.0f / sum;

    // ---- write normalized P bf16 into this wave's private (now-dead) q rows ----
    short* pbase = &q_lds[w * 16 * QS];
    #pragma unroll
    for (int mt = 0; mt < 4; ++mt) {
        bf16x4 pk;
        #pragma unroll
        for (int j = 0; j < 4; ++j) pk[j] = f2bf(p[mt][j] * rs);
        *(bf16x4*)(pbase + r * PS + 16 * mt + 4 * g) = pk;   // P[s_local=r][t]
    }

    // ---- PV: outT = vT @ PT ; B-frags from P (row r, t contiguous) ----
    bf16x8 bp0 = *(const bf16x8*)(pbase + r * PS + 8 * g);
    bf16x8 bp1 = *(const bf16x8*)(pbase + r * PS + 8 * g + 32);

    const int srow = 16 * w + r;
    const bool valid = srow < HALFS;
    float* orow = out + (size_t)batch * (SEQ * HEAD) + (size_t)(half * HALFS + srow) * HEAD;
    #pragma unroll
    for (int mt = 0; mt < 12; ++mt) {
        const short* vb = &xv_lds[(16 * mt + r) * VS + 8 * g];
        f32x4 acc = {0.f, 0.f, 0.f, 0.f};
        acc = __builtin_amdgcn_mfma_f32_16x16x32_bf16(*(const bf16x8*)(vb),      bp0, acc, 0, 0, 0);
        acc = __builtin_amdgcn_mfma_f32_16x16x32_bf16(*(const bf16x8*)(vb + 32), bp1, acc, 0, 0, 0);
        if (valid) {   // C col = s(=r), rows = h contiguous -> float4 store
            float4 st; st.x = acc[0]; st.y = acc[1]; st.z = acc[2]; st.w = acc[3];
            *(float4*)(orow + 16 * mt + 4 * g) = st;
        }
    }
}

extern "C" void kernel_launch(void* const* d_in, const int* in_sizes, int n_in,
                              void* d_out, int out_size, void* d_ws, size_t ws_size,
                              hipStream_t stream) {
    const float* x  = (const float*)d_in[0];
    const float* Wq = (const float*)d_in[1];
    const float* Wk = (const float*)d_in[2];
    const float* Wv = (const float*)d_in[3];
    short* wt = (short*)d_ws;                       // needs 3*192*128*2 = 147456 B
    int B = in_sizes[0] / (SEQ * EMB);              // 8192
    wt_prep<<<(3 * WMAT) / 256, 256, 0, stream>>>(Wq, Wk, Wv, wt);
    attn_head<<<2 * B, 256, 0, stream>>>(x, wt, (float*)d_out);
}

// Round 2
// 883.245 us; speedup vs baseline: 1.0278x; 1.0278x over previous
//
#include <hip/hip_runtime.h>
#include <hip/hip_bf16.h>

#define SEQ   110
#define HALFS 55
#define EMB   102
#define HEAD  192

typedef short bf16x8 __attribute__((ext_vector_type(8)));
typedef short bf16x4 __attribute__((ext_vector_type(4)));
typedef float f32x4  __attribute__((ext_vector_type(4)));

#define XS    104             // x tile row stride (shorts), 13 granules (odd)
#define QS    200             // q/k row stride, 25 granules (odd)
#define VS    72              // vT row stride, 9 granules (odd)
#define PS    72              // P row stride
#define WES   128             // Wt e-stride (padded 102->128)
#define WMAT  (HEAD * WES)
#define XTILE (64 * XS)       // 6656 shorts per half-tile

__device__ __forceinline__ short f2bf(float f) {
    unsigned u = __float_as_uint(f);
    unsigned r = u + 0x7fffu + ((u >> 16) & 1u);   // RNE
    return (short)(r >> 16);
}
__device__ __forceinline__ unsigned pk2(float a, float b) {
    return ((unsigned)(unsigned short)f2bf(b) << 16) | (unsigned short)f2bf(a);
}

// Wt[m][h][e] = W_m[e][h] in bf16, zero-padded e->128; Wq pre-scaled by 1/sqrt(HEAD).
__global__ void wt_prep(const float* __restrict__ Wq, const float* __restrict__ Wk,
                        const float* __restrict__ Wv, short* __restrict__ wt) {
    int flat = blockIdx.x * 256 + threadIdx.x;     // < 3*WMAT
    int m   = flat / WMAT;
    int rem = flat - m * WMAT;
    int h = rem >> 7;
    int e = rem & 127;
    const float* W = (m == 0) ? Wq : (m == 1) ? Wk : Wv;
    float v = (e < EMB) ? W[e * HEAD + h] : 0.0f;
    if (m == 0) v *= 0.07216878364870322f;         // 1/sqrt(192) folded into Wq
    wt[flat] = f2bf(v);
}

// One block per (batch, half). Grid layout: [0,B) = half 0, [B,2B) = half 1
// so a batch's two blocks land on the same XCD (shared x tile in local L2).
__global__ __launch_bounds__(256, 3)
void attn_head(const float* __restrict__ x, const short* __restrict__ wt,
               float* __restrict__ out, int B) {
    const int bid   = blockIdx.x;
    const int half  = (bid >= B) ? 1 : 0;
    const int batch = bid - half * B;
    const int tid   = threadIdx.x;
    const int w     = tid >> 6;
    const int lane  = tid & 63;
    const int g     = lane >> 4;
    const int r     = lane & 15;

    // u1: x two tiles (13312 shorts) -> later vT (13824 shorts)
    // u2: q -> k -> P (wave-private row reuse, no extra barriers for q/P)
    __shared__ __attribute__((aligned(16))) short u1[192 * VS];   // 27648 B
    __shared__ __attribute__((aligned(16))) short u2[64 * QS];    // 25600 B

    // ---- zero only the pad: rows 55..63 of both tiles + cols 102/103 rows 0..54 ----
    {
        unsigned long long* z = (unsigned long long*)u1;
        #pragma unroll
        for (int i0 = 0; i0 < 2; ++i0) {
            int i = tid + i0 * 256;
            if (i < 468) z[(i < 234 ? 1430 : 2860) + i] = 0ull;  // 2x 234 u64 pad-row blocks
        }
        if (tid < 110) {
            int row = tid >> 1, tile = tid & 1;
            *(unsigned*)(u1 + tile * XTILE + row * XS + 102) = 0u;
        }
    }

    // ---- stage x[batch] -> bf16 tiles; loads issued up-front, 2x u32 stores per quad ----
    {
        const float4* xb4 = (const float4*)(x + (size_t)batch * (SEQ * EMB));
        float4 xr[11];
        #pragma unroll
        for (int it = 0; it < 10; ++it) xr[it] = xb4[tid + it * 256];
        if (tid < 245) xr[10] = xb4[tid + 2560];          // 2805 float4 total
        #pragma unroll
        for (int it = 0; it < 11; ++it) {
            if (it == 10 && tid >= 245) continue;
            int fc  = (tid + it * 256) * 4;
            int row = (int)(((unsigned long long)fc * 41121ull) >> 22);  // /102
            int e   = fc - row * EMB;
            int tile = row >= HALFS;
            int lr   = row - HALFS * tile;
            int cross = (e == 100);
            int rowb  = row + cross;
            int tileb = rowb >= HALFS;
            int lrb   = rowb - HALFS * tileb;
            int ba = tile * XTILE + lr * XS + e;
            int bb = cross ? (tileb * XTILE + lrb * XS) : (ba + 2);
            float4 v4 = xr[it];
            *(unsigned*)(u1 + ba) = pk2(v4.x, v4.y);
            *(unsigned*)(u1 + bb) = pk2(v4.z, v4.w);
        }
    }
    __syncthreads();   // barrier 1: pad zeros + x staged

    const short* x_own = u1 + half * XTILE;
    const short* x_oth = u1 + (half ^ 1) * XTILE;
    const short* wtq = wt;
    const short* wtk = wt + WMAT;
    const short* wtv = wt + 2 * WMAT;

    // ---- x B-frags (wave's 16 s-rows: 16w+r) ----
    bf16x8 bxq[4], bxk[4];
    {
        const short* bo = x_own + (16 * w + r) * XS;
        const short* bt = x_oth + (16 * w + r) * XS;
        #pragma unroll
        for (int kk = 0; kk < 3; ++kk) {
            bxq[kk] = *(const bf16x8*)(bo + 32 * kk + 8 * g);
            bxk[kk] = *(const bf16x8*)(bt + 32 * kk + 8 * g);
        }
        bf16x8 zz = {};
        bxq[3] = zz; bxk[3] = zz;
        if (g == 0) {
            bxq[3] = *(const bf16x8*)(bo + 96);
            bxk[3] = *(const bf16x8*)(bt + 96);
        }
    }

    // ---- q-GEMM: qT tiles -> u2 rows 16w+r (wave-private) ----
    #pragma unroll
    for (int mt = 0; mt < 12; ++mt) {
        const short* wb = wtq + (16 * mt + r) * WES + 8 * g;
        f32x4 acc = {0.f, 0.f, 0.f, 0.f};
        #pragma unroll
        for (int kk = 0; kk < 4; ++kk)
            acc = __builtin_amdgcn_mfma_f32_16x16x32_bf16(
                *(const bf16x8*)(wb + 32 * kk), bxq[kk], acc, 0, 0, 0);
        bf16x4 pk;
        #pragma unroll
        for (int j = 0; j < 4; ++j) pk[j] = f2bf(acc[j]);
        *(bf16x4*)(&u2[(16 * w + r) * QS + 16 * mt + 4 * g]) = pk;
    }

    // ---- read q score-B-frags back (same wave, same rows: no barrier needed) ----
    bf16x8 bq[6];
    {
        const short* qb = &u2[(16 * w + r) * QS + 8 * g];
        #pragma unroll
        for (int kk = 0; kk < 6; ++kk) bq[kk] = *(const bf16x8*)(qb + 32 * kk);
    }

    // ---- k-GEMM: overwrite same wave-private rows of u2 (ordered after bq reads) ----
    #pragma unroll
    for (int mt = 0; mt < 12; ++mt) {
        const short* wb = wtk + (16 * mt + r) * WES + 8 * g;
        f32x4 acc = {0.f, 0.f, 0.f, 0.f};
        #pragma unroll
        for (int kk = 0; kk < 4; ++kk)
            acc = __builtin_amdgcn_mfma_f32_16x16x32_bf16(
                *(const bf16x8*)(wb + 32 * kk), bxk[kk], acc, 0, 0, 0);
        bf16x4 pk;
        #pragma unroll
        for (int j = 0; j < 4; ++j) pk[j] = f2bf(acc[j]);
        *(bf16x4*)(&u2[(16 * w + r) * QS + 16 * mt + 4 * g]) = pk;
    }

    // ---- v-GEMM: accumulate, pack to bf16 immediately (24 VGPR, not 48) ----
    bf16x8 bv[3][4];
    #pragma unroll
    for (int i = 0; i < 3; ++i) {
        const short* wb = wtv + (16 * (w + 4 * i) + r) * WES + 8 * g;
        #pragma unroll
        for (int kk = 0; kk < 4; ++kk) bv[i][kk] = *(const bf16x8*)(wb + 32 * kk);
    }
    unsigned vpk[4][3][2];
    #pragma unroll
    for (int mt = 0; mt < 4; ++mt) {
        const short* ab = x_oth + (16 * mt + r) * XS;
        bf16x8 a[4];
        #pragma unroll
        for (int kk = 0; kk < 3; ++kk) a[kk] = *(const bf16x8*)(ab + 32 * kk + 8 * g);
        bf16x8 zz = {};
        a[3] = zz;
        if (g == 0) a[3] = *(const bf16x8*)(ab + 96);
        #pragma unroll
        for (int i = 0; i < 3; ++i) {
            f32x4 acc = {0.f, 0.f, 0.f, 0.f};
            #pragma unroll
            for (int kk = 0; kk < 4; ++kk)
                acc = __builtin_amdgcn_mfma_f32_16x16x32_bf16(
                    a[kk], bv[i][kk], acc, 0, 0, 0);
            vpk[mt][i][0] = pk2(acc[0], acc[1]);
            vpk[mt][i][1] = pk2(acc[2], acc[3]);
        }
    }

    __syncthreads();   // barrier 2: x reads done (all waves), k rows all written

    // ---- write vT over dead x region ----
    #pragma unroll
    for (int mt = 0; mt < 4; ++mt) {
        #pragma unroll
        for (int i = 0; i < 3; ++i) {
            int h = 16 * (w + 4 * i) + r;
            *(unsigned*)(&u1[h * VS + 16 * mt + 4 * g])     = vpk[mt][i][0];
            *(unsigned*)(&u1[h * VS + 16 * mt + 4 * g + 2]) = vpk[mt][i][1];
        }
    }

    // ---- scoresT = k @ qT (A = k rows from u2, B = bq regs) ----
    float sc[4][4];
    #pragma unroll
    for (int mt = 0; mt < 4; ++mt) {
        const short* kb = &u2[(16 * mt + r) * QS + 8 * g];
        f32x4 acc = {0.f, 0.f, 0.f, 0.f};
        #pragma unroll
        for (int kk = 0; kk < 6; ++kk)
            acc = __builtin_amdgcn_mfma_f32_16x16x32_bf16(
                *(const bf16x8*)(kb + 32 * kk), bq[kk], acc, 0, 0, 0);
        #pragma unroll
        for (int j = 0; j < 4; ++j) sc[mt][j] = acc[j];
    }
    #pragma unroll
    for (int j = 0; j < 4; ++j)
        if (48 + 4 * g + j >= HALFS) sc[3][j] = -1e30f;   // key padding

    // ---- softmax over t (16 in-lane + 2 shfl_xor over g-groups) ----
    float mx = -1e30f;
    #pragma unroll
    for (int mt = 0; mt < 4; ++mt) {
        #pragma unroll
        for (int j = 0; j < 4; ++j) mx = fmaxf(mx, sc[mt][j]);
    }
    mx = fmaxf(mx, __shfl_xor(mx, 16));
    mx = fmaxf(mx, __shfl_xor(mx, 32));
    float p[4][4];
    float sum = 0.f;
    #pragma unroll
    for (int mt = 0; mt < 4; ++mt) {
        #pragma unroll
        for (int j = 0; j < 4; ++j) { p[mt][j] = __expf(sc[mt][j] - mx); sum += p[mt][j]; }
    }
    sum += __shfl_xor(sum, 16);
    sum += __shfl_xor(sum, 32);
    float rs = 1.0f / sum;

    __syncthreads();   // barrier 3: all k reads + vT writes done

    // ---- P into wave-private u2 area; read B-frags back (same wave, no barrier) ----
    short* pbase = &u2[w * 16 * QS];
    #pragma unroll
    for (int mt = 0; mt < 4; ++mt) {
        *(unsigned*)(pbase + r * PS + 16 * mt + 4 * g)     = pk2(p[mt][0] * rs, p[mt][1] * rs);
        *(unsigned*)(pbase + r * PS + 16 * mt + 4 * g + 2) = pk2(p[mt][2] * rs, p[mt][3] * rs);
    }
    bf16x8 bp0 = *(const bf16x8*)(pbase + r * PS + 8 * g);
    bf16x8 bp1 = *(const bf16x8*)(pbase + r * PS + 8 * g + 32);

    // ---- PV: outT = vT @ PT; C cols = s(=r), rows = h contiguous -> float4 stores ----
    const int srow = 16 * w + r;
    const bool valid = srow < HALFS;
    float* orow = out + (size_t)batch * (SEQ * HEAD) + (size_t)(half * HALFS + srow) * HEAD;
    #pragma unroll
    for (int mt = 0; mt < 12; ++mt) {
        const short* vb = &u1[(16 * mt + r) * VS + 8 * g];
        f32x4 acc = {0.f, 0.f, 0.f, 0.f};
        acc = __builtin_amdgcn_mfma_f32_16x16x32_bf16(*(const bf16x8*)(vb),      bp0, acc, 0, 0, 0);
        acc = __builtin_amdgcn_mfma_f32_16x16x32_bf16(*(const bf16x8*)(vb + 32), bp1, acc, 0, 0, 0);
        if (valid) {
            float4 st; st.x = acc[0]; st.y = acc[1]; st.z = acc[2]; st.w = acc[3];
            *(float4*)(orow + 16 * mt + 4 * g) = st;
        }
    }
}

extern "C" void kernel_launch(void* const* d_in, const int* in_sizes, int n_in,
                              void* d_out, int out_size, void* d_ws, size_t ws_size,
                              hipStream_t stream) {
    const float* x  = (const float*)d_in[0];
    const float* Wq = (const float*)d_in[1];
    const float* Wk = (const float*)d_in[2];
    const float* Wv = (const float*)d_in[3];
    short* wt = (short*)d_ws;                       // 3*192*128*2 = 147456 B
    int B = in_sizes[0] / (SEQ * EMB);              // 8192
    wt_prep<<<(3 * WMAT) / 256, 256, 0, stream>>>(Wq, Wk, Wv, wt);
    attn_head<<<2 * B, 256, 0, stream>>>(x, wt, (float*)d_out, B);
}

// Round 3
// 449.368 us; speedup vs baseline: 2.0202x; 1.9655x over previous
//
#include <hip/hip_runtime.h>
#include <hip/hip_bf16.h>

#define SEQ   110
#define HALFS 55
#define EMB   102
#define HEAD  192

typedef short bf16x8 __attribute__((ext_vector_type(8)));
typedef short bf16x4 __attribute__((ext_vector_type(4)));
typedef float f32x4  __attribute__((ext_vector_type(4)));

#define XS    104             // x tile row stride (shorts), odd granules
#define QS    200             // q/k row stride
#define VS    72              // vT row stride
#define PS    72              // P row stride
#define WES   128             // Wt e-stride (padded 102->128)
#define WMAT  (HEAD * WES)
#define XTILE (64 * XS)       // 6656 shorts per half tile
#define UPB   32              // units per block (units = (batch,half) pairs)

__device__ __forceinline__ short f2bf(float f) {
    unsigned u = __float_as_uint(f);
    unsigned r = u + 0x7fffu + ((u >> 16) & 1u);   // RNE
    return (short)(r >> 16);
}
__device__ __forceinline__ unsigned pk2(float a, float b) {
    return ((unsigned)(unsigned short)f2bf(b) << 16) | (unsigned short)f2bf(a);
}

// Wt[m][h][e] = W_m[e][h] bf16, zero-padded e->128; Wq pre-scaled by 1/sqrt(HEAD).
__global__ void wt_prep(const float* __restrict__ Wq, const float* __restrict__ Wk,
                        const float* __restrict__ Wv, short* __restrict__ wt) {
    int flat = blockIdx.x * 256 + threadIdx.x;
    int m   = flat / WMAT;
    int rem = flat - m * WMAT;
    int h = rem >> 7;
    int e = rem & 127;
    const float* W = (m == 0) ? Wq : (m == 1) ? Wk : Wv;
    float v = (e < EMB) ? W[e * HEAD + h] : 0.0f;
    if (m == 0) v *= 0.07216878364870322f;
    wt[flat] = f2bf(v);
}

// Persistent-ish blocks: 512 blocks x UPB units. Unit u -> batch u>>1, half u&1.
// Weights live in VGPRs for the whole block (h-ownership: wave w owns h-tiles w,w+4,w+8).
__global__ __launch_bounds__(256, 2)
void attn_head(const float* __restrict__ x, const short* __restrict__ wt,
               float* __restrict__ out, int B) {
    const int tid  = threadIdx.x;
    const int w    = tid >> 6;
    const int lane = tid & 63;
    const int g    = lane >> 4;
    const int r    = lane & 15;

    __shared__ __attribute__((aligned(16))) short u1[HEAD * VS];   // 27648 B: x tiles / vT overlay
    __shared__ __attribute__((aligned(16))) short q_lds[64 * QS];  // 25600 B
    __shared__ __attribute__((aligned(16))) short k_lds[64 * QS];  // 25600 B

    // ---- hoist all weight fragments into registers (unit-invariant) ----
    const short* wtq = wt;
    const short* wtk = wt + WMAT;
    const short* wtv = wt + 2 * WMAT;
    bf16x8 wqf[3][4], wkf[3][4], wvf[3][4];
    #pragma unroll
    for (int mi = 0; mi < 3; ++mi) {
        const int hrow = 16 * (w + 4 * mi) + r;
        #pragma unroll
        for (int kk = 0; kk < 4; ++kk) {
            wqf[mi][kk] = *(const bf16x8*)(wtq + hrow * WES + 32 * kk + 8 * g);
            wkf[mi][kk] = *(const bf16x8*)(wtk + hrow * WES + 32 * kk + 8 * g);
            wvf[mi][kk] = *(const bf16x8*)(wtv + hrow * WES + 32 * kk + 8 * g);
        }
    }

    // ---- precompute staging LDS offsets (unit-invariant, packed ba|bb<<16) ----
    unsigned soff[11];
    #pragma unroll
    for (int it = 0; it < 11; ++it) {
        int i4 = tid + it * 256;
        if (i4 < 2805) {
            int fc  = i4 * 4;
            int row = (int)(((unsigned long long)fc * 41121ull) >> 22);  // /102
            int e   = fc - row * EMB;
            int tile = row >= HALFS;
            int lr   = row - HALFS * tile;
            int cross = (e == 100);
            int rowb  = row + cross;
            int tileb = rowb >= HALFS;
            int lrb   = rowb - HALFS * tileb;
            int ba = tile * XTILE + lr * XS + e;
            int bb = cross ? (tileb * XTILE + lrb * XS) : (ba + 2);
            soff[it] = (unsigned)ba | ((unsigned)bb << 16);
        } else soff[it] = 0xFFFFFFFFu;
    }

    const int u0 = blockIdx.x * UPB;
    unsigned xv0[11], xv1[11];

    // prefetch x for the first batch
    {
        const float4* xb4 = (const float4*)(x + (size_t)(u0 >> 1) * (SEQ * EMB));
        #pragma unroll
        for (int it = 0; it < 11; ++it) {
            int i4 = tid + it * 256;
            if (i4 < 2805) { float4 v = xb4[i4]; xv0[it] = pk2(v.x, v.y); xv1[it] = pk2(v.z, v.w); }
        }
    }

    for (int i = 0; i < UPB; ++i) {
        const int u     = u0 + i;
        const int batch = u >> 1;
        const int half  = u & 1;

        // ---- stage: pad zeros + x stores from registers ----
        {
            unsigned long long* z = (unsigned long long*)u1;
            #pragma unroll
            for (int i0 = 0; i0 < 2; ++i0) {
                int ii = tid + i0 * 256;
                if (ii < 468) z[(ii < 234 ? 1430 : 2860) + ii] = 0ull;
            }
            if (tid < 110) {
                int row = tid >> 1, tile = tid & 1;
                *(unsigned*)(u1 + tile * XTILE + row * XS + 102) = 0u;
            }
            #pragma unroll
            for (int it = 0; it < 11; ++it) {
                if (soff[it] != 0xFFFFFFFFu) {
                    int ba = (int)(soff[it] & 0xFFFFu), bb = (int)(soff[it] >> 16);
                    *(unsigned*)(u1 + ba) = xv0[it];
                    *(unsigned*)(u1 + bb) = xv1[it];
                }
            }
        }
        __syncthreads();   // bar A: x + zeros visible

        // prefetch next batch during the odd unit (xv already consumed)
        if (half == 1 && i + 1 < UPB) {
            const float4* xb4 = (const float4*)(x + (size_t)(batch + 1) * (SEQ * EMB));
            #pragma unroll
            for (int it = 0; it < 11; ++it) {
                int i4 = tid + it * 256;
                if (i4 < 2805) { float4 v = xb4[i4]; xv0[it] = pk2(v.x, v.y); xv1[it] = pk2(v.z, v.w); }
            }
        }

        const short* x_own = u1 + half * XTILE;
        const short* x_oth = u1 + (half ^ 1) * XTILE;

        // ---- q-GEMM (A = wq regs, B = x_own rows): wave covers h-tiles {w,w+4,w+8}, all st ----
        #pragma unroll
        for (int st = 0; st < 4; ++st) {
            const short* bo = x_own + (16 * st + r) * XS;
            bf16x8 bx[4];
            #pragma unroll
            for (int kk = 0; kk < 3; ++kk) bx[kk] = *(const bf16x8*)(bo + 32 * kk + 8 * g);
            bf16x8 zz = {};
            bx[3] = zz;
            if (g == 0) bx[3] = *(const bf16x8*)(bo + 96);
            #pragma unroll
            for (int mi = 0; mi < 3; ++mi) {
                f32x4 acc = {0.f, 0.f, 0.f, 0.f};
                #pragma unroll
                for (int kk = 0; kk < 4; ++kk)
                    acc = __builtin_amdgcn_mfma_f32_16x16x32_bf16(wqf[mi][kk], bx[kk], acc, 0, 0, 0);
                bf16x4 pk;
                #pragma unroll
                for (int j = 0; j < 4; ++j) pk[j] = f2bf(acc[j]);
                *(bf16x4*)(&q_lds[(16 * st + r) * QS + 16 * (w + 4 * mi) + 4 * g]) = pk;
            }
        }

        // ---- k-GEMM + v-GEMM share x_oth fragments ----
        unsigned vpk[4][3][2];
        #pragma unroll
        for (int st = 0; st < 4; ++st) {
            const short* bt = x_oth + (16 * st + r) * XS;
            bf16x8 bx[4];
            #pragma unroll
            for (int kk = 0; kk < 3; ++kk) bx[kk] = *(const bf16x8*)(bt + 32 * kk + 8 * g);
            bf16x8 zz = {};
            bx[3] = zz;
            if (g == 0) bx[3] = *(const bf16x8*)(bt + 96);
            #pragma unroll
            for (int mi = 0; mi < 3; ++mi) {
                f32x4 acc = {0.f, 0.f, 0.f, 0.f};
                #pragma unroll
                for (int kk = 0; kk < 4; ++kk)
                    acc = __builtin_amdgcn_mfma_f32_16x16x32_bf16(wkf[mi][kk], bx[kk], acc, 0, 0, 0);
                bf16x4 pk;
                #pragma unroll
                for (int j = 0; j < 4; ++j) pk[j] = f2bf(acc[j]);
                *(bf16x4*)(&k_lds[(16 * st + r) * QS + 16 * (w + 4 * mi) + 4 * g]) = pk;
            }
            #pragma unroll
            for (int mi = 0; mi < 3; ++mi) {
                f32x4 acc = {0.f, 0.f, 0.f, 0.f};
                #pragma unroll
                for (int kk = 0; kk < 4; ++kk)
                    acc = __builtin_amdgcn_mfma_f32_16x16x32_bf16(bx[kk], wvf[mi][kk], acc, 0, 0, 0);
                vpk[st][mi][0] = pk2(acc[0], acc[1]);
                vpk[st][mi][1] = pk2(acc[2], acc[3]);
            }
        }

        __syncthreads();   // bar B: x reads done; q/k fully written

        // ---- vT writes over dead x region ----
        #pragma unroll
        for (int st = 0; st < 4; ++st) {
            #pragma unroll
            for (int mi = 0; mi < 3; ++mi) {
                int h = 16 * (w + 4 * mi) + r;
                *(unsigned*)(&u1[h * VS + 16 * st + 4 * g])     = vpk[st][mi][0];
                *(unsigned*)(&u1[h * VS + 16 * st + 4 * g + 2]) = vpk[st][mi][1];
            }
        }

        // ---- scoresT = k @ qT for wave's query tile st=w ----
        bf16x8 bq[6];
        {
            const short* qb = &q_lds[(16 * w + r) * QS + 8 * g];
            #pragma unroll
            for (int kk = 0; kk < 6; ++kk) bq[kk] = *(const bf16x8*)(qb + 32 * kk);
        }
        float sc[4][4];
        #pragma unroll
        for (int mt = 0; mt < 4; ++mt) {
            const short* kb = &k_lds[(16 * mt + r) * QS + 8 * g];
            f32x4 acc = {0.f, 0.f, 0.f, 0.f};
            #pragma unroll
            for (int kk = 0; kk < 6; ++kk)
                acc = __builtin_amdgcn_mfma_f32_16x16x32_bf16(
                    *(const bf16x8*)(kb + 32 * kk), bq[kk], acc, 0, 0, 0);
            #pragma unroll
            for (int j = 0; j < 4; ++j) sc[mt][j] = acc[j];
        }
        #pragma unroll
        for (int j = 0; j < 4; ++j)
            if (48 + 4 * g + j >= HALFS) sc[3][j] = -1e30f;

        float mx = -1e30f;
        #pragma unroll
        for (int mt = 0; mt < 4; ++mt) {
            #pragma unroll
            for (int j = 0; j < 4; ++j) mx = fmaxf(mx, sc[mt][j]);
        }
        mx = fmaxf(mx, __shfl_xor(mx, 16));
        mx = fmaxf(mx, __shfl_xor(mx, 32));
        float p[4][4];
        float sum = 0.f;
        #pragma unroll
        for (int mt = 0; mt < 4; ++mt) {
            #pragma unroll
            for (int j = 0; j < 4; ++j) { p[mt][j] = __expf(sc[mt][j] - mx); sum += p[mt][j]; }
        }
        sum += __shfl_xor(sum, 16);
        sum += __shfl_xor(sum, 32);
        float rs = 1.0f / sum;

        // ---- P into wave-private q rows (in-wave write->read, no barrier) ----
        short* pbase = &q_lds[w * 16 * QS];
        #pragma unroll
        for (int mt = 0; mt < 4; ++mt) {
            *(unsigned*)(pbase + r * PS + 16 * mt + 4 * g)     = pk2(p[mt][0] * rs, p[mt][1] * rs);
            *(unsigned*)(pbase + r * PS + 16 * mt + 4 * g + 2) = pk2(p[mt][2] * rs, p[mt][3] * rs);
        }
        bf16x8 bp0 = *(const bf16x8*)(pbase + r * PS + 8 * g);
        bf16x8 bp1 = *(const bf16x8*)(pbase + r * PS + 8 * g + 32);

        __syncthreads();   // bar C: vT writes visible

        // ---- PV: outT = vT @ PT ----
        const int srow  = 16 * w + r;
        const bool valid = srow < HALFS;
        float* orow = out + (size_t)batch * (SEQ * HEAD) + (size_t)(half * HALFS + srow) * HEAD;
        #pragma unroll
        for (int mt = 0; mt < 12; ++mt) {
            const short* vb = &u1[(16 * mt + r) * VS + 8 * g];
            f32x4 acc = {0.f, 0.f, 0.f, 0.f};
            acc = __builtin_amdgcn_mfma_f32_16x16x32_bf16(*(const bf16x8*)(vb),      bp0, acc, 0, 0, 0);
            acc = __builtin_amdgcn_mfma_f32_16x16x32_bf16(*(const bf16x8*)(vb + 32), bp1, acc, 0, 0, 0);
            if (valid) {
                float4 st; st.x = acc[0]; st.y = acc[1]; st.z = acc[2]; st.w = acc[3];
                *(float4*)(orow + 16 * mt + 4 * g) = st;
            }
        }

        __syncthreads();   // bar D: vT reads done before next unit's staging overwrites u1
    }
}

extern "C" void kernel_launch(void* const* d_in, const int* in_sizes, int n_in,
                              void* d_out, int out_size, void* d_ws, size_t ws_size,
                              hipStream_t stream) {
    const float* x  = (const float*)d_in[0];
    const float* Wq = (const float*)d_in[1];
    const float* Wk = (const float*)d_in[2];
    const float* Wv = (const float*)d_in[3];
    short* wt = (short*)d_ws;                       // 3*192*128*2 = 147456 B
    int B = in_sizes[0] / (SEQ * EMB);              // 8192
    int nblocks = (2 * B + UPB - 1) / UPB;          // 512
    wt_prep<<<(3 * WMAT) / 256, 256, 0, stream>>>(Wq, Wk, Wv, wt);
    attn_head<<<nblocks, 256, 0, stream>>>(x, wt, (float*)d_out, B);
}